// Round 5
// baseline (149.094 us; speedup 1.0000x reference)
//
#include <hip/hip_runtime.h>
#include <math.h>

// Problem constants (from reference)
#define BB    2
#define TT    64
#define NN    128
#define TN    8192      // TT*NN
#define MM    16384     // BB*TN
#define CMAP  2048
#define CCOMP 32
#define FHW   256       // 16*16

// fused-kernel geometry: 64 blocks x 256 threads = 16384 threads (1 per token)
#define NBLK   64
#define NTHR   256
#define CSPLIT 32       // comp partial splits (1 per block per batch)
#define CRANGE 64       // CMAP / CSPLIT

// ---- moment-contraction attention ----
// sigmoid(z)-0.5 ~ odd degree-17 Chebyshev poly P(z) on [-ZFIT,ZFIT] (host fit).
// z = a0 + b1*u + c1*v with u,v = (xr-256)/256 in [-1.004,1.004].
// sum_k P(z_k)*{1,u,v} = contraction of per-query coeffs against query-
// independent moments M_{j,l} = sum_k u^j v^l  (j+l <= DEG+1).
#define DEG    17
#define NS     18
#define NODD   9
#define MDIM   19
#define NMOMF  (MDIM*MDIM)  // 361 (padded table, j+l<=18 valid)
#define MCH    32           // k-chunks per batch (32 x 2 batches = 64 blocks)
#define MPTS   256          // TN / MCH points per chunk = block size
#define ZFIT   5.0
#define ZFITF  5.0f
#define UVBOUND 1.0045f

struct QCoef { float cb[NS][NODD]; };   // cb[s][q] = C_{s+t}*binom(s+t,s)

// workspace layout (float offsets)
#define OFF_CP    0                                  // CSPLIT*BB*FHW*CCOMP = 524288
#define OFF_COMP  (OFF_CP + CSPLIT*BB*FHW*CCOMP)     // 16384
#define OFF_X     (OFF_COMP + BB*FHW*CCOMP)          // MM*2
#define OFF_MP    (OFF_X + MM*2)                     // BB*MCH*NMOMF = 23104
// total ~ 596K floats = 2.4 MB

// ---- monotonic grid barrier ----
// Counters live in __device__ globals: zero-initialized at module load,
// persist across graph replays, NOT in the poisoned workspace -> no reset
// dispatch needed. Target = (my/NBLK+1)*NBLK, monotone across iterations
// (stream-serialized replays). Device-scope atomics + __threadfence for
// cross-XCD visibility (Guideline 16). Safe: 64 blocks <= 256 CUs, all
// co-resident by construction.
#define NBAR 4
__device__ unsigned g_bar[NBAR];

__device__ __forceinline__ void grid_bar(int ph) {
    __syncthreads();
    if (threadIdx.x == 0) {
        __threadfence();                               // release
        unsigned my  = atomicAdd(&g_bar[ph], 1u);
        unsigned tgt = (my / NBLK + 1u) * NBLK;
        while (atomicAdd(&g_bar[ph], 0u) < tgt)
            __builtin_amdgcn_s_sleep(1);
    }
    __syncthreads();
    __threadfence();                                   // acquire (all waves)
}

__device__ __forceinline__ float fast_sigmoid(float v) {
    return __builtin_amdgcn_rcpf(1.0f + __expf(-v));
}
__device__ __forceinline__ float fast_tanh(float v) {
    return 1.0f - 2.0f * __builtin_amdgcn_rcpf(1.0f + __expf(2.0f * v));
}

// ===== single fused kernel: comp -> reduce -> token -> moments -> query =====
__global__ void __launch_bounds__(256) k_fused(
        const float* __restrict__ x,
        const float* __restrict__ metadata,
        const float* __restrict__ w_ih,
        const float* __restrict__ b_ih,  const float* __restrict__ b_hh,
        const float* __restrict__ fc_w,  const float* __restrict__ fc_b,
        const float* __restrict__ fc2_w, const float* __restrict__ fc2_b,
        const float* __restrict__ fc3_w, const float* __restrict__ fc3_b,
        const float* __restrict__ comp_w, const float* __restrict__ comp_b,
        const float* __restrict__ vf_w,  const float* __restrict__ vf_b,
        const float* __restrict__ fcout_w, const float* __restrict__ fcout_b,
        float* __restrict__ ws, float* __restrict__ y, QCoef qc) {

    // LDS union across phases (barriers separate uses):
    //  P1a: wcs[CRANGE][CCOMP]     =  8 KB
    //  P4 : spu/spv[MPTS][MDIM]    = 39 KB
    //  P5 : sM[NMOMF]              = 1.4 KB
    __shared__ float lds[2 * MPTS * MDIM];

    float* Cp      = ws + OFF_CP;
    float* comp_ws = ws + OFF_COMP;
    float2* Xr     = (float2*)(ws + OFF_X);
    float* Mp      = ws + OFF_MP;

    const int blk = blockIdx.x;
    const int tid = threadIdx.x;
    const int m   = blk * NTHR + tid;      // global token id (phases 3 & 5)

    // ---------------- P1a: comp partials ----------------
    {
        const int b  = blk >> 5;           // 0..1
        const int cs = blk & 31;           // 0..31
        float (*wcs)[CCOMP] = (float(*)[CCOMP])lds;
        for (int i = tid; i < CRANGE * CCOMP; i += NTHR) {
            int c = i >> 5, o = i & 31;
            wcs[c][o] = comp_w[o * CMAP + cs * CRANGE + c];
        }
        __syncthreads();

        float acc[CCOMP];
#pragma unroll
        for (int o = 0; o < CCOMP; o++) acc[o] = 0.0f;

        const float* mb = metadata + ((size_t)b * CMAP + (size_t)cs * CRANGE) * FHW + tid;
#pragma unroll 4
        for (int c = 0; c < CRANGE; c++) {
            float mv = mb[c * FHW];
#pragma unroll
            for (int o = 0; o < CCOMP; o++) acc[o] += mv * wcs[c][o];
        }

        float* outp = Cp + (size_t)cs * (BB * FHW * CCOMP) + ((size_t)b * FHW + tid) * CCOMP;
#pragma unroll
        for (int o = 0; o < CCOMP; o += 4)
            *(float4*)&outp[o] = make_float4(acc[o], acc[o + 1], acc[o + 2], acc[o + 3]);
    }
    grid_bar(0);

    // ---------------- P1b: comp reduce ----------------
    {
        float s = 0.0f;
#pragma unroll
        for (int cs = 0; cs < CSPLIT; cs++)
            s += Cp[(size_t)cs * (BB * FHW * CCOMP) + m];
        comp_ws[m] = s + comp_b[m & (CCOMP - 1)];
    }
    grid_bar(1);

    // ---------------- P2: token (PE+LSTM+sample+vf+Q proj) ----------------
    float al, be, ga;                      // kept in registers for P5
    {
        const int b = m >> 13;
        const int p = m & (TN - 1);
        const int t = p >> 7;

        const float px = x[(size_t)(b * 2 + 0) * TN + p];
        const float py = x[(size_t)(b * 2 + 1) * TN + p];

        const float xr0 = px + __sinf((float)t);
        const float xr1 = py + __cosf((float)t);
        Xr[m] = make_float2(xr0, xr1);

        float X[4];
#pragma unroll
        for (int j = 0; j < 4; j++) {
            float gi = xr0 * w_ih[(j)      * 2] + xr1 * w_ih[(j)      * 2 + 1] + b_ih[j]      + b_hh[j];
            float gg = xr0 * w_ih[(8 + j)  * 2] + xr1 * w_ih[(8 + j)  * 2 + 1] + b_ih[8 + j]  + b_hh[8 + j];
            float go = xr0 * w_ih[(12 + j) * 2] + xr1 * w_ih[(12 + j) * 2 + 1] + b_ih[12 + j] + b_hh[12 + j];
            float cst = fast_sigmoid(gi) * fast_tanh(gg);
            X[j] = fast_sigmoid(go) * fast_tanh(cst);
        }

        float lc[CCOMP];
#pragma unroll
        for (int c = 0; c < CCOMP; c++) lc[c] = 0.0f;

        const float ix = px * (1.0f / 32.0f) - 0.5f;
        const float iy = py * (1.0f / 32.0f) - 0.5f;
        const float fx0 = floorf(ix), fy0 = floorf(iy);
        const float wx = ix - fx0, wy = iy - fy0;
        const int x0 = (int)fx0, y0 = (int)fy0;
        const float* cb = comp_ws + (size_t)b * FHW * CCOMP;

#pragma unroll
        for (int dy = 0; dy < 2; dy++) {
#pragma unroll
            for (int dx = 0; dx < 2; dx++) {
                int xx = x0 + dx, yy = y0 + dy;
                if (xx < 0 || xx > 15 || yy < 0 || yy > 15) continue;
                float w = (dy ? wy : 1.0f - wy) * (dx ? wx : 1.0f - wx);
                const float4* cp4 = (const float4*)(cb + (yy * 16 + xx) * CCOMP);
#pragma unroll
                for (int c4 = 0; c4 < CCOMP / 4; c4++) {
                    float4 v = cp4[c4];
                    lc[c4 * 4 + 0] += w * v.x;
                    lc[c4 * 4 + 1] += w * v.y;
                    lc[c4 * 4 + 2] += w * v.z;
                    lc[c4 * 4 + 3] += w * v.w;
                }
            }
        }

        float X2[4];
#pragma unroll
        for (int j = 0; j < 4; j++) {
            float a = vf_b[j];
#pragma unroll
            for (int k = 0; k < 4; k++) a += X[k] * vf_w[j * 36 + k];
#pragma unroll
            for (int c = 0; c < CCOMP; c++) a += lc[c] * vf_w[j * 36 + 4 + c];
            X2[j] = a;
        }

        al = 0.0f; be = 0.0f; ga = 0.0f;
#pragma unroll
        for (int d = 0; d < 8; d++) {
            float q = fc_b[d];
#pragma unroll
            for (int k = 0; k < 4; k++) q += X2[k] * fc_w[d * 4 + k];
            al += q * fc2_b[d];
            be += q * fc2_w[d * 2];
            ga += q * fc2_w[d * 2 + 1];
        }
    }
    grid_bar(2);

    // ---------------- P4: bivariate moments ----------------
    {
        const int b3 = blk >> 5;
        const int ch = blk & 31;
        float (*spu)[MDIM] = (float(*)[MDIM])lds;
        float (*spv)[MDIM] = (float(*)[MDIM])(lds + MPTS * MDIM);

        float2 xv = Xr[b3 * TN + ch * MPTS + tid];
        const float u = (xv.x - 256.0f) * (1.0f / 256.0f);
        const float v = (xv.y - 256.0f) * (1.0f / 256.0f);
        float a = 1.0f, c = 1.0f;
#pragma unroll
        for (int i = 0; i < MDIM; i++) {
            spu[tid][i] = a; spv[tid][i] = c;
            a *= u; c *= v;
        }
        __syncthreads();

        float* outp = Mp + ((size_t)(b3 * MCH + ch)) * NMOMF;
        for (int i = tid; i < NMOMF; i += NTHR) {
            const int j = i / MDIM, l = i % MDIM;
            float s = 0.0f;
            if (j + l < MDIM) {
#pragma unroll 8
                for (int p = 0; p < MPTS; p++)
                    s += spu[p][j] * spv[p][l];
            }
            outp[i] = s;
        }
    }
    grid_bar(3);

    // ---------------- P5: per-query contraction + epilogue ----------------
    {
        const int b = m >> 13;             // uniform per block
        const int p = m & (TN - 1);
        float* sM = lds;

        for (int i = tid; i < NMOMF; i += NTHR) {
            float s = 0.0f;
            for (int ch = 0; ch < MCH; ch++)
                s += Mp[((size_t)(b * MCH + ch)) * NMOMF + i];
            sM[i] = s;
        }
        __syncthreads();

        const float b1 = 256.0f * be;
        const float c1 = 256.0f * ga;
        const float a0 = al + 256.0f * (be + ga);   // z = a0 + b1*u + c1*v

        float S0, S1, S2;
        const float zb = fabsf(a0) + UVBOUND * (fabsf(b1) + fabsf(c1));
        if (zb >= ZFITF) {
            // exact fallback (expected never taken; guards poly range)
            float s0 = 0.0f, s1 = 0.0f, s2 = 0.0f;
            const float2* xp = Xr + b * TN;
            for (int k = 0; k < TN; k++) {
                float2 kv = xp[k];
                float z = al + be * kv.x + ga * kv.y;
                float sg = fast_sigmoid(z);
                s0 += sg; s1 += sg * kv.x; s2 += sg * kv.y;
            }
            S0 = s0; S1 = s1; S2 = s2;
        } else {
            float pa[NS];
            pa[0] = 1.0f;
#pragma unroll
            for (int t = 1; t < NS; t++) pa[t] = pa[t - 1] * a0;

            float A[NS];
#pragma unroll
            for (int s = 0; s < NS; s++) {
                float acc = 0.0f;
                const int t0 = (s & 1) ? 0 : 1;
#pragma unroll
                for (int q = 0; q < NODD; q++) {
                    const int t = t0 + 2 * q;
                    if (s + t <= DEG) acc = fmaf(qc.cb[s][q], pa[t], acc);
                }
                A[s] = acc;
            }

            float R0 = A[0] * sM[0];
            float R1 = A[0] * sM[1 * MDIM + 0];
            float R2 = A[0] * sM[0 * MDIM + 1];

            float Ep[NS], Ec[NS];
            Ep[0] = 1.0f;
#pragma unroll
            for (int s = 1; s < NS; s++) {
                Ec[0] = c1 * Ep[0];
#pragma unroll
                for (int j = 1; j < NS; j++)
                    if (j < s) Ec[j] = fmaf(b1, Ep[j - 1], c1 * Ep[j]);
                Ec[s] = b1 * Ep[s - 1];

                float W = 0.0f, W1 = 0.0f, W2 = 0.0f;
#pragma unroll
                for (int j = 0; j < NS; j++) {
                    if (j <= s) {
                        const int l = s - j;
                        const float e = Ec[j];
                        W  = fmaf(e, sM[j * MDIM + l],       W);
                        W1 = fmaf(e, sM[(j + 1) * MDIM + l], W1);
                        W2 = fmaf(e, sM[j * MDIM + l + 1],   W2);
                    }
                }
                R0 = fmaf(A[s], W,  R0);
                R1 = fmaf(A[s], W1, R1);
                R2 = fmaf(A[s], W2, R2);
#pragma unroll
                for (int j = 0; j < NS; j++)
                    if (j <= s) Ep[j] = Ec[j];
            }

            S0 = 4096.0f + R0;                              // sum sigma
            const float su = 0.5f * sM[1 * MDIM + 0] + R1;  // sum sigma*u
            const float sv = 0.5f * sM[0 * MDIM + 1] + R2;  // sum sigma*v
            S1 = 256.0f * su + 256.0f * S0;
            S2 = 256.0f * sv + 256.0f * S0;
        }

        float f0 = fcout_b[0], f1 = fcout_b[1];
#pragma unroll
        for (int d = 0; d < 8; d++) {
            float vv = S0 * fc3_b[d] + S1 * fc3_w[d * 2] + S2 * fc3_w[d * 2 + 1];
            vv = (vv > 0.5f) ? vv : 0.0f;
            f0 += vv * fcout_w[d];
            f1 += vv * fcout_w[8 + d];
        }
        y[(size_t)(b * 2 + 0) * TN + p] = f0;
        y[(size_t)(b * 2 + 1) * TN + p] = f1;
    }
}

// ---- host-side: degree-17 odd Chebyshev fit of sigmoid(z)-0.5 on [-ZFIT,ZFIT],
// converted to z-monomial coeffs pre-multiplied by binomials. Pure f64 CPU
// math, no HIP calls -> safe under graph capture (runs once, static init).
static QCoef compute_qcoef() {
    const int NNODE = 64;
    const double PI = 3.14159265358979323846;
    double term[NODD];
    for (int i = 0; i < NODD; ++i) term[i] = 0.0;

    for (int jn = 0; jn < NNODE; ++jn) {
        double theta = (jn + 0.5) * (PI / NNODE);
        double ct = cos(theta);
        double zj = ZFIT * ct;
        double fj = 1.0 / (1.0 + exp(-zj)) - 0.5;
        double Ckm2 = 1.0, Ckm1 = ct;
        term[0] += fj * ct;
        int idx = 1;
        for (int k = 2; k <= DEG; ++k) {
            double Ck = 2.0 * ct * Ckm1 - Ckm2;
            Ckm2 = Ckm1; Ckm1 = Ck;
            if (k & 1) term[idx++] += fj * Ck;
        }
    }

    double c[DEG + 1];
    for (int i = 0; i <= DEG; ++i) c[i] = 0.0;
    for (int i = 0; i < NODD; ++i) c[2 * i + 1] = term[i] * (2.0 / NNODE);

    double Tm2[DEG + 1], Tm1[DEG + 1], a[DEG + 1];
    for (int i = 0; i <= DEG; ++i) { Tm2[i] = 0.0; Tm1[i] = 0.0; a[i] = 0.0; }
    Tm2[0] = 1.0; Tm1[1] = 1.0;
    a[1] = c[1];
    for (int k = 2; k <= DEG; ++k) {
        double Tc[DEG + 1];
        for (int mm = 0; mm <= DEG; ++mm) Tc[mm] = 0.0;
        for (int mm = 0; mm <= k; ++mm) {
            double vv = -Tm2[mm];
            if (mm > 0) vv += 2.0 * Tm1[mm - 1];
            Tc[mm] = vv;
        }
        if (k & 1)
            for (int mm = 1; mm <= k; mm += 2) a[mm] += c[k] * Tc[mm];
        for (int mm = 0; mm <= DEG; ++mm) { Tm2[mm] = Tm1[mm]; Tm1[mm] = Tc[mm]; }
    }

    double Cz[DEG + 1];
    double sc = 1.0;
    for (int mm = 0; mm <= DEG; ++mm) { Cz[mm] = a[mm] * sc; sc *= (1.0 / ZFIT); }

    double Bi[NS][NS];
    for (int n = 0; n < NS; ++n)
        for (int k = 0; k < NS; ++k) Bi[n][k] = 0.0;
    for (int n = 0; n < NS; ++n) {
        Bi[n][0] = 1.0;
        for (int k = 1; k <= n; ++k)
            Bi[n][k] = Bi[n - 1][k - 1] + ((k <= n - 1) ? Bi[n - 1][k] : 0.0);
    }

    QCoef qc;
    for (int s = 0; s < NS; ++s)
        for (int q = 0; q < NODD; ++q) qc.cb[s][q] = 0.0f;
    for (int s = 0; s < NS; ++s) {
        int q = 0;
        for (int t = (s & 1) ? 0 : 1; s + t <= DEG; t += 2)
            qc.cb[s][q++] = (float)(Cz[s + t] * Bi[s + t][s]);
    }
    return qc;
}

extern "C" void kernel_launch(void* const* d_in, const int* in_sizes, int n_in,
                              void* d_out, int out_size, void* d_ws, size_t ws_size,
                              hipStream_t stream) {
    const float* x        = (const float*)d_in[0];
    const float* metadata = (const float*)d_in[1];
    const float* w_ih     = (const float*)d_in[2];
    // d_in[3] = w_hh: unused (h0 = 0)
    const float* b_ih     = (const float*)d_in[4];
    const float* b_hh     = (const float*)d_in[5];
    const float* fc_w     = (const float*)d_in[6];
    const float* fc_b     = (const float*)d_in[7];
    const float* fc2_w    = (const float*)d_in[8];
    const float* fc2_b    = (const float*)d_in[9];
    const float* fc3_w    = (const float*)d_in[10];
    const float* fc3_b    = (const float*)d_in[11];
    const float* comp_w   = (const float*)d_in[12];
    const float* comp_b   = (const float*)d_in[13];
    const float* vf_w     = (const float*)d_in[14];
    const float* vf_b     = (const float*)d_in[15];
    const float* fcout_w  = (const float*)d_in[16];
    const float* fcout_b  = (const float*)d_in[17];

    static const QCoef qc = compute_qcoef();   // host f64 fit, once

    k_fused<<<NBLK, NTHR, 0, stream>>>(x, metadata, w_ih, b_ih, b_hh,
                                       fc_w, fc_b, fc2_w, fc2_b,
                                       fc3_w, fc3_b, comp_w, comp_b,
                                       vf_w, vf_b, fcout_w, fcout_b,
                                       (float*)d_ws, (float*)d_out, qc);
}

// Round 6
// 113.606 us; speedup vs baseline: 1.3124x; 1.3124x over previous
//
#include <hip/hip_runtime.h>
#include <math.h>

// Problem constants (from reference)
#define BB    2
#define TT    64
#define NN    128
#define TN    8192      // TT*NN
#define MM    16384     // BB*TN
#define CMAP  2048
#define CCOMP 32
#define FHW   256       // 16*16

// comp partial split (proven in round-4 k_comp_p: 128 blocks, ~coalesced)
#define CSPLIT 64
#define CRANGE 32       // CMAP / CSPLIT

// ---- moment-contraction attention ----
// sigmoid(z)-0.5 ~ odd degree-17 Chebyshev poly P(z) on [-ZFIT,ZFIT] (host fit).
// z = a0 + b1*u + c1*v with u,v = (xr-256)/256 in [-1.004,1.004].
// sum_k P(z_k)*{1,u,v} = contraction of per-query coeffs against query-
// independent moments M_{j,l} = sum_k u^j v^l  (j+l <= DEG+1).
// KEY: moments depend only on Xr = x + PE, NOT on the comp/LSTM path, so
// comp partials and moment partials run in ONE kernel with no ordering.
#define DEG    17
#define NS     18
#define NODD   9
#define MDIM   19
#define NMOMF  (MDIM*MDIM)  // 361 (padded table, j+l<=18 valid)
#define MCH    64           // k-chunks per batch
#define MPTS   128          // TN / MCH points per chunk
#define ZFIT   5.0
#define ZFITF  5.0f
#define UVBOUND 1.0045f

struct QCoef { float cb[NS][NODD]; };   // cb[s][q] = C_{s+t}*binom(s+t,s)

// workspace layout (float offsets)
#define OFF_CP    0                                  // CSPLIT*BB*FHW*CCOMP = 1048576
#define OFF_COMP  (OFF_CP + CSPLIT*BB*FHW*CCOMP)     // 16384
#define OFF_X     (OFF_COMP + BB*FHW*CCOMP)          // MM*2 = 32768
#define OFF_MP    (OFF_X + MM*2)                     // BB*MCH*NMOMF = 46208
#define OFF_MF    (OFF_MP + BB*MCH*NMOMF)            // BB*NMOMF (pad 1024)
// total ~ 1.15M floats = 4.6 MB

__device__ __forceinline__ float fast_sigmoid(float v) {
    return __builtin_amdgcn_rcpf(1.0f + __expf(-v));
}
__device__ __forceinline__ float fast_tanh(float v) {
    return 1.0f - 2.0f * __builtin_amdgcn_rcpf(1.0f + __expf(2.0f * v));
}

// ===== K1: comp partials (blocks 0..127) + Xr & moment partials (128..255) ==
// Two independent roles, no cross-block dependency inside the kernel.
__global__ void __launch_bounds__(256) k_pre(const float* __restrict__ x,
                                             const float* __restrict__ metadata,
                                             const float* __restrict__ comp_w,
                                             float* __restrict__ Cp,
                                             float2* __restrict__ Xr,
                                             float* __restrict__ Mp) {
    // LDS union: comp role uses wcs[32][32] (4 KB); moment role uses
    // spu/spv[MPTS][MDIM] (19 KB).
    __shared__ float lds[2 * MPTS * MDIM];

    const int blk = blockIdx.x;
    const int tid = threadIdx.x;

    if (blk < 128) {
        // ---- comp partials (identical math to round-4 k_comp_p) ----
        const int b  = blk & 1;
        const int cs = blk >> 1;           // 0..63
        float (*wcs)[CCOMP] = (float(*)[CCOMP])lds;
        for (int i = tid; i < CRANGE * CCOMP; i += 256) {
            int c = i >> 5, o = i & 31;
            wcs[c][o] = comp_w[o * CMAP + cs * CRANGE + c];
        }
        __syncthreads();

        float acc[CCOMP];
#pragma unroll
        for (int o = 0; o < CCOMP; o++) acc[o] = 0.0f;

        const float* mb = metadata + ((size_t)b * CMAP + (size_t)cs * CRANGE) * FHW + tid;
#pragma unroll 4
        for (int c = 0; c < CRANGE; c++) {
            float mv = mb[c * FHW];
#pragma unroll
            for (int o = 0; o < CCOMP; o++) acc[o] += mv * wcs[c][o];
        }

        float* outp = Cp + (size_t)cs * (BB * FHW * CCOMP) + ((size_t)b * FHW + tid) * CCOMP;
#pragma unroll
        for (int o = 0; o < CCOMP; o += 4)
            *(float4*)&outp[o] = make_float4(acc[o], acc[o + 1], acc[o + 2], acc[o + 3]);
    } else {
        // ---- Xr + moment partials (identical math to round-4 k_mom) ----
        const int idx = blk - 128;
        const int b  = idx & 1;
        const int ch = idx >> 1;           // 0..63
        float (*spu)[MDIM] = (float(*)[MDIM])lds;
        float (*spv)[MDIM] = (float(*)[MDIM])(lds + MPTS * MDIM);

        if (tid < MPTS) {
            const int p = ch * MPTS + tid;
            const int t = p >> 7;
            const float px = x[(size_t)(b * 2 + 0) * TN + p];
            const float py = x[(size_t)(b * 2 + 1) * TN + p];
            const float xr0 = px + __sinf((float)t);
            const float xr1 = py + __cosf((float)t);
            Xr[b * TN + p] = make_float2(xr0, xr1);

            const float u = (xr0 - 256.0f) * (1.0f / 256.0f);
            const float v = (xr1 - 256.0f) * (1.0f / 256.0f);
            float a = 1.0f, c = 1.0f;
#pragma unroll
            for (int i = 0; i < MDIM; i++) {
                spu[tid][i] = a; spv[tid][i] = c;
                a *= u; c *= v;
            }
        }
        __syncthreads();

        float* outp = Mp + ((size_t)(b * MCH + ch)) * NMOMF;
        for (int i = tid; i < NMOMF; i += 256) {
            const int j = i / MDIM, l = i % MDIM;
            float s = 0.0f;
            if (j + l < MDIM) {
#pragma unroll 8
                for (int p = 0; p < MPTS; p++)
                    s += spu[p][j] * spv[p][l];
            }
            outp[i] = s;
        }
    }
}

// ===== K2: comp reduce + bias (blocks 0..63); moment reduce (64..67) ========
__global__ void __launch_bounds__(256) k_reduce(const float* __restrict__ Cp,
                                                const float* __restrict__ comp_b,
                                                float* __restrict__ comp_ws,
                                                const float* __restrict__ Mp,
                                                float* __restrict__ Mf) {
    const int blk = blockIdx.x;
    const int tid = threadIdx.x;

    if (blk < 64) {
        const int i = blk * 256 + tid;     // 0..16383
        float s = 0.0f;
#pragma unroll 16
        for (int cs = 0; cs < CSPLIT; cs++)
            s += Cp[(size_t)cs * (BB * FHW * CCOMP) + i];
        comp_ws[i] = s + comp_b[i & (CCOMP - 1)];
    } else {
        const int gi = (blk - 64) * 256 + tid;   // 0..1023, need 722
        if (gi < BB * NMOMF) {
            const int b = gi / NMOMF;
            const int i = gi - b * NMOMF;
            float s = 0.0f;
#pragma unroll 16
            for (int ch = 0; ch < MCH; ch++)      // ascending ch: same order as before
                s += Mp[((size_t)(b * MCH + ch)) * NMOMF + i];
            Mf[gi] = s;
        }
    }
}

// ===== K3: token (PE+LSTM+sample+vf+Qproj, regs) + contraction + epilogue ===
__global__ void __launch_bounds__(256) k_main(
        const float* __restrict__ x,
        const float* __restrict__ w_ih,
        const float* __restrict__ b_ih,  const float* __restrict__ b_hh,
        const float* __restrict__ fc_w,  const float* __restrict__ fc_b,
        const float* __restrict__ fc2_w, const float* __restrict__ fc2_b,
        const float* __restrict__ fc3_w, const float* __restrict__ fc3_b,
        const float* __restrict__ vf_w,  const float* __restrict__ vf_b,
        const float* __restrict__ fcout_w, const float* __restrict__ fcout_b,
        const float* __restrict__ comp_ws,
        const float2* __restrict__ Xr,
        const float* __restrict__ Mf,
        float* __restrict__ y, QCoef qc) {
    __shared__ float sM[NMOMF];

    const int tid = threadIdx.x;
    const int m   = blockIdx.x * 256 + tid;
    const int b   = m >> 13;               // uniform per block
    const int p   = m & (TN - 1);
    const int t   = p >> 7;

    // issue the moment-table broadcast load early (overlaps token math)
    for (int i = tid; i < NMOMF; i += 256) sM[i] = Mf[b * NMOMF + i];

    // ---- token math ----
    const float px = x[(size_t)(b * 2 + 0) * TN + p];
    const float py = x[(size_t)(b * 2 + 1) * TN + p];
    const float xr0 = px + __sinf((float)t);
    const float xr1 = py + __cosf((float)t);

    float X[4];
#pragma unroll
    for (int j = 0; j < 4; j++) {
        float gi = xr0 * w_ih[(j)      * 2] + xr1 * w_ih[(j)      * 2 + 1] + b_ih[j]      + b_hh[j];
        float gg = xr0 * w_ih[(8 + j)  * 2] + xr1 * w_ih[(8 + j)  * 2 + 1] + b_ih[8 + j]  + b_hh[8 + j];
        float go = xr0 * w_ih[(12 + j) * 2] + xr1 * w_ih[(12 + j) * 2 + 1] + b_ih[12 + j] + b_hh[12 + j];
        float cst = fast_sigmoid(gi) * fast_tanh(gg);
        X[j] = fast_sigmoid(go) * fast_tanh(cst);
    }

    float lc[CCOMP];
#pragma unroll
    for (int c = 0; c < CCOMP; c++) lc[c] = 0.0f;

    const float ix = px * (1.0f / 32.0f) - 0.5f;
    const float iy = py * (1.0f / 32.0f) - 0.5f;
    const float fx0 = floorf(ix), fy0 = floorf(iy);
    const float wx = ix - fx0, wy = iy - fy0;
    const int x0 = (int)fx0, y0 = (int)fy0;
    const float* cb = comp_ws + (size_t)b * FHW * CCOMP;

#pragma unroll
    for (int dy = 0; dy < 2; dy++) {
#pragma unroll
        for (int dx = 0; dx < 2; dx++) {
            int xx = x0 + dx, yy = y0 + dy;
            if (xx < 0 || xx > 15 || yy < 0 || yy > 15) continue;
            float w = (dy ? wy : 1.0f - wy) * (dx ? wx : 1.0f - wx);
            const float4* cp4 = (const float4*)(cb + (yy * 16 + xx) * CCOMP);
#pragma unroll
            for (int c4 = 0; c4 < CCOMP / 4; c4++) {
                float4 v = cp4[c4];
                lc[c4 * 4 + 0] += w * v.x;
                lc[c4 * 4 + 1] += w * v.y;
                lc[c4 * 4 + 2] += w * v.z;
                lc[c4 * 4 + 3] += w * v.w;
            }
        }
    }

    float X2[4];
#pragma unroll
    for (int j = 0; j < 4; j++) {
        float a = vf_b[j];
#pragma unroll
        for (int k = 0; k < 4; k++) a += X[k] * vf_w[j * 36 + k];
#pragma unroll
        for (int c = 0; c < CCOMP; c++) a += lc[c] * vf_w[j * 36 + 4 + c];
        X2[j] = a;
    }

    float al = 0.0f, be = 0.0f, ga = 0.0f;
#pragma unroll
    for (int d = 0; d < 8; d++) {
        float q = fc_b[d];
#pragma unroll
        for (int k = 0; k < 4; k++) q += X2[k] * fc_w[d * 4 + k];
        al += q * fc2_b[d];
        be += q * fc2_w[d * 2];
        ga += q * fc2_w[d * 2 + 1];
    }

    __syncthreads();   // sM ready

    // ---- contraction ----
    const float b1 = 256.0f * be;
    const float c1 = 256.0f * ga;
    const float a0 = al + 256.0f * (be + ga);   // z = a0 + b1*u + c1*v

    float S0, S1, S2;
    const float zb = fabsf(a0) + UVBOUND * (fabsf(b1) + fabsf(c1));
    if (zb >= ZFITF) {
        // exact fallback (expected never taken; guards poly range)
        float s0 = 0.0f, s1 = 0.0f, s2 = 0.0f;
        const float2* xp = Xr + b * TN;
        for (int k = 0; k < TN; k++) {
            float2 kv = xp[k];
            float z = al + be * kv.x + ga * kv.y;
            float sg = fast_sigmoid(z);
            s0 += sg; s1 += sg * kv.x; s2 += sg * kv.y;
        }
        S0 = s0; S1 = s1; S2 = s2;
    } else {
        float pa[NS];
        pa[0] = 1.0f;
#pragma unroll
        for (int tt = 1; tt < NS; tt++) pa[tt] = pa[tt - 1] * a0;

        float A[NS];
#pragma unroll
        for (int s = 0; s < NS; s++) {
            float acc = 0.0f;
            const int t0 = (s & 1) ? 0 : 1;
#pragma unroll
            for (int q = 0; q < NODD; q++) {
                const int tt = t0 + 2 * q;
                if (s + tt <= DEG) acc = fmaf(qc.cb[s][q], pa[tt], acc);
            }
            A[s] = acc;
        }

        float R0 = A[0] * sM[0];
        float R1 = A[0] * sM[1 * MDIM + 0];
        float R2 = A[0] * sM[0 * MDIM + 1];

        float Ep[NS], Ec[NS];
        Ep[0] = 1.0f;
#pragma unroll
        for (int s = 1; s < NS; s++) {
            Ec[0] = c1 * Ep[0];
#pragma unroll
            for (int j = 1; j < NS; j++)
                if (j < s) Ec[j] = fmaf(b1, Ep[j - 1], c1 * Ep[j]);
            Ec[s] = b1 * Ep[s - 1];

            float W = 0.0f, W1 = 0.0f, W2 = 0.0f;
#pragma unroll
            for (int j = 0; j < NS; j++) {
                if (j <= s) {
                    const int l = s - j;
                    const float e = Ec[j];
                    W  = fmaf(e, sM[j * MDIM + l],       W);
                    W1 = fmaf(e, sM[(j + 1) * MDIM + l], W1);
                    W2 = fmaf(e, sM[j * MDIM + l + 1],   W2);
                }
            }
            R0 = fmaf(A[s], W,  R0);
            R1 = fmaf(A[s], W1, R1);
            R2 = fmaf(A[s], W2, R2);
#pragma unroll
            for (int j = 0; j < NS; j++)
                if (j <= s) Ep[j] = Ec[j];
        }

        S0 = 4096.0f + R0;                              // sum sigma
        const float su = 0.5f * sM[1 * MDIM + 0] + R1;  // sum sigma*u
        const float sv = 0.5f * sM[0 * MDIM + 1] + R2;  // sum sigma*v
        S1 = 256.0f * su + 256.0f * S0;
        S2 = 256.0f * sv + 256.0f * S0;
    }

    // ---- epilogue ----
    float f0 = fcout_b[0], f1 = fcout_b[1];
#pragma unroll
    for (int d = 0; d < 8; d++) {
        float vv = S0 * fc3_b[d] + S1 * fc3_w[d * 2] + S2 * fc3_w[d * 2 + 1];
        vv = (vv > 0.5f) ? vv : 0.0f;
        f0 += vv * fcout_w[d];
        f1 += vv * fcout_w[8 + d];
    }
    y[(size_t)(b * 2 + 0) * TN + p] = f0;
    y[(size_t)(b * 2 + 1) * TN + p] = f1;
}

// ---- host-side: degree-17 odd Chebyshev fit of sigmoid(z)-0.5 on [-ZFIT,ZFIT],
// converted to z-monomial coeffs pre-multiplied by binomials. Pure f64 CPU
// math, no HIP calls -> safe under graph capture (runs once, static init).
static QCoef compute_qcoef() {
    const int NNODE = 64;
    const double PI = 3.14159265358979323846;
    double term[NODD];
    for (int i = 0; i < NODD; ++i) term[i] = 0.0;

    for (int jn = 0; jn < NNODE; ++jn) {
        double theta = (jn + 0.5) * (PI / NNODE);
        double ct = cos(theta);
        double zj = ZFIT * ct;
        double fj = 1.0 / (1.0 + exp(-zj)) - 0.5;
        double Ckm2 = 1.0, Ckm1 = ct;
        term[0] += fj * ct;
        int idx = 1;
        for (int k = 2; k <= DEG; ++k) {
            double Ck = 2.0 * ct * Ckm1 - Ckm2;
            Ckm2 = Ckm1; Ckm1 = Ck;
            if (k & 1) term[idx++] += fj * Ck;
        }
    }

    double c[DEG + 1];
    for (int i = 0; i <= DEG; ++i) c[i] = 0.0;
    for (int i = 0; i < NODD; ++i) c[2 * i + 1] = term[i] * (2.0 / NNODE);

    double Tm2[DEG + 1], Tm1[DEG + 1], a[DEG + 1];
    for (int i = 0; i <= DEG; ++i) { Tm2[i] = 0.0; Tm1[i] = 0.0; a[i] = 0.0; }
    Tm2[0] = 1.0; Tm1[1] = 1.0;
    a[1] = c[1];
    for (int k = 2; k <= DEG; ++k) {
        double Tc[DEG + 1];
        for (int mm = 0; mm <= DEG; ++mm) Tc[mm] = 0.0;
        for (int mm = 0; mm <= k; ++mm) {
            double vv = -Tm2[mm];
            if (mm > 0) vv += 2.0 * Tm1[mm - 1];
            Tc[mm] = vv;
        }
        if (k & 1)
            for (int mm = 1; mm <= k; mm += 2) a[mm] += c[k] * Tc[mm];
        for (int mm = 0; mm <= DEG; ++mm) { Tm2[mm] = Tm1[mm]; Tm1[mm] = Tc[mm]; }
    }

    double Cz[DEG + 1];
    double sc = 1.0;
    for (int mm = 0; mm <= DEG; ++mm) { Cz[mm] = a[mm] * sc; sc *= (1.0 / ZFIT); }

    double Bi[NS][NS];
    for (int n = 0; n < NS; ++n)
        for (int k = 0; k < NS; ++k) Bi[n][k] = 0.0;
    for (int n = 0; n < NS; ++n) {
        Bi[n][0] = 1.0;
        for (int k = 1; k <= n; ++k)
            Bi[n][k] = Bi[n - 1][k - 1] + ((k <= n - 1) ? Bi[n - 1][k] : 0.0);
    }

    QCoef qc;
    for (int s = 0; s < NS; ++s)
        for (int q = 0; q < NODD; ++q) qc.cb[s][q] = 0.0f;
    for (int s = 0; s < NS; ++s) {
        int q = 0;
        for (int t = (s & 1) ? 0 : 1; s + t <= DEG; t += 2)
            qc.cb[s][q++] = (float)(Cz[s + t] * Bi[s + t][s]);
    }
    return qc;
}

extern "C" void kernel_launch(void* const* d_in, const int* in_sizes, int n_in,
                              void* d_out, int out_size, void* d_ws, size_t ws_size,
                              hipStream_t stream) {
    const float* x        = (const float*)d_in[0];
    const float* metadata = (const float*)d_in[1];
    const float* w_ih     = (const float*)d_in[2];
    // d_in[3] = w_hh: unused (h0 = 0)
    const float* b_ih     = (const float*)d_in[4];
    const float* b_hh     = (const float*)d_in[5];
    const float* fc_w     = (const float*)d_in[6];
    const float* fc_b     = (const float*)d_in[7];
    const float* fc2_w    = (const float*)d_in[8];
    const float* fc2_b    = (const float*)d_in[9];
    const float* fc3_w    = (const float*)d_in[10];
    const float* fc3_b    = (const float*)d_in[11];
    const float* comp_w   = (const float*)d_in[12];
    const float* comp_b   = (const float*)d_in[13];
    const float* vf_w     = (const float*)d_in[14];
    const float* vf_b     = (const float*)d_in[15];
    const float* fcout_w  = (const float*)d_in[16];
    const float* fcout_b  = (const float*)d_in[17];

    static const QCoef qc = compute_qcoef();   // host f64 fit, once

    float*  ws      = (float*)d_ws;
    float*  Cp      = ws + OFF_CP;
    float*  comp_ws = ws + OFF_COMP;
    float2* Xr      = (float2*)(ws + OFF_X);
    float*  Mp      = ws + OFF_MP;
    float*  Mf      = ws + OFF_MF;

    k_pre<<<256, 256, 0, stream>>>(x, metadata, comp_w, Cp, Xr, Mp);

    k_reduce<<<68, 256, 0, stream>>>(Cp, comp_b, comp_ws, Mp, Mf);

    k_main<<<64, 256, 0, stream>>>(x, w_ih, b_ih, b_hh,
                                   fc_w, fc_b, fc2_w, fc2_b,
                                   fc3_w, fc3_b, vf_w, vf_b,
                                   fcout_w, fcout_b,
                                   comp_ws, Xr, Mf, (float*)d_out, qc);
}